// Round 1
// baseline (358.742 us; speedup 1.0000x reference)
//
#include <hip/hip_runtime.h>
#include <hip/hip_bf16.h>
#include <math.h>

typedef __attribute__((ext_vector_type(8))) short short8;
typedef __attribute__((ext_vector_type(4))) float f32x4;

__device__ __forceinline__ short f2bf(float x) {
    union { float f; unsigned u; } v; v.f = x;
    unsigned r = v.u + 0x7fffu + ((v.u >> 16) & 1u);   // RNE
    return (short)(r >> 16);
}

// ---------------------------------------------------------------- tables
__global__ void tab_init(float* __restrict__ tab4096, float* __restrict__ tab512) {
    int i = blockIdx.x * 256 + threadIdx.x;
    if (i < 4096) {
        float sn, cs;
        sincospif((float)i * (1.0f / 2048.0f), &sn, &cs);   // 2*pi*i/4096
        tab4096[2 * i] = cs; tab4096[2 * i + 1] = sn;
    }
    if (i < 512) {
        float sn, cs;
        sincospif((float)i * (1.0f / 256.0f), &sn, &cs);    // 2*pi*i/512
        tab512[2 * i] = cs; tab512[2 * i + 1] = sn;
    }
}

// ---------------------------------------------------------------- temporal DFT (32 modes of rfft(T=4096))
__global__ __launch_bounds__(256) void dft_time_kernel(const float* __restrict__ spikes,
                                                       const float* __restrict__ tab4096,
                                                       float* __restrict__ xr, float* __restrict__ xi)
{
    __shared__ float  sp[4096];
    __shared__ float2 tw[4096];
    int row = blockIdx.x;                    // b*512 + n, 1024 rows
    int tid = threadIdx.x;
    const float*  s  = spikes + (size_t)row * 4096;
    const float2* t4 = (const float2*)tab4096;
    for (int i = tid; i < 4096; i += 256) { sp[i] = s[i]; tw[i] = t4[i]; }
    __syncthreads();
    int k = tid >> 3, l8 = tid & 7;          // 32 modes x 8 threads
    float ar = 0.f, ai = 0.f;
    int idx  = (k * l8) & 4095;
    int step = (k * 8) & 4095;
    for (int t = l8; t < 4096; t += 8) {
        float v = sp[t];
        float2 cs = tw[idx];
        ar += v * cs.x;                      // X[k] = sum x * e^{-2pi i k t / T}
        ai -= v * cs.y;
        idx = (idx + step) & 4095;
    }
    #pragma unroll
    for (int m = 1; m < 8; m <<= 1) { ar += __shfl_xor(ar, m); ai += __shfl_xor(ai, m); }
    if (l8 == 0) { xr[row * 32 + k] = ar; xi[row * 32 + k] = ai; }
}

// ---------------------------------------------------------------- mode-energy E[b,n,d]
__global__ __launch_bounds__(128) void energy_kernel(const float* __restrict__ xr, const float* __restrict__ xi,
                                                     const float* __restrict__ Wr, const float* __restrict__ Wi,
                                                     float* __restrict__ E)
{
    __shared__ float sxr[32], sxi[32];
    int row = blockIdx.x, tid = threadIdx.x;
    if (tid < 32) { sxr[tid] = xr[row * 32 + tid]; sxi[tid] = xi[row * 32 + tid]; }
    __syncthreads();
    float acc = 0.f;
    #pragma unroll 8
    for (int k = 0; k < 32; ++k) {
        float a = sxr[k], b = sxi[k];
        float wr = Wr[k * 128 + tid], wi = Wi[k * 128 + tid];
        float yr = a * wr - b * wi;
        float yi = a * wi + b * wr;
        acc += sqrtf(yr * yr + yi * yi + 1e-8f);
    }
    E[row * 128 + tid] = acc * (1.0f / 32.0f);
}

// ---------------------------------------------------------------- generic small linear: C = act(A @ W + bias)
template<int K, int NOUT, bool RELU>
__global__ void lin_kernel(const float* __restrict__ A, const float* __restrict__ W,
                           const float* __restrict__ bias, float* __restrict__ C)
{
    __shared__ float arow[K];
    int row = blockIdx.x, tid = threadIdx.x;
    for (int i = tid; i < K; i += NOUT) arow[i] = A[(size_t)row * K + i];
    __syncthreads();
    float acc = bias ? bias[tid] : 0.0f;
    #pragma unroll 8
    for (int i = 0; i < K; ++i) acc += arow[i] * W[i * NOUT + tid];
    if (RELU) acc = fmaxf(acc, 0.0f);
    C[(size_t)row * NOUT + tid] = acc;
}

// ---------------------------------------------------------------- pack ew2 [256x128] fp32 -> bf16 in B-fragment order
// layout: [kk 0..7][nf 0..7][lane 0..63][j 0..7],  k = kk*32 + (lane>>4)*8 + j, n = nf*16 + (lane&15)
__global__ void pack_ew2(const float* __restrict__ ew2, short* __restrict__ out) {
    int i = blockIdx.x * 256 + threadIdx.x;     // 32768
    int j = i & 7, lane = (i >> 3) & 63, nf = (i >> 9) & 7, kk = i >> 12;
    int k = kk * 32 + (lane >> 4) * 8 + j;
    int n = nf * 16 + (lane & 15);
    out[i] = f2bf(ew2[k * 128 + n]);
}

// ---------------------------------------------------------------- edge MLP (the heavy part), MFMA bf16
// per block: one (b,s) and a 128-wide t-tile; computes coeffs cr/ci[b,s,t]
__global__ __launch_bounds__(256) void edge_mfma(
    const float* __restrict__ ps, const float* __restrict__ pt,
    const float* __restrict__ eb1, const short* __restrict__ ew2p,
    const float* __restrict__ eb2, const float* __restrict__ ew3,
    const float* __restrict__ eb3, float* __restrict__ cr, float* __restrict__ ci)
{
    __shared__ __align__(16) short ew2s[32768];   // 64KB bf16 fragments
    __shared__ __align__(16) float psp[256];      // ps[s,:] + eb1
    __shared__ float eb2s[128];
    __shared__ float ew3s[256];                   // [n][j], j fast

    int bidx  = blockIdx.x;                 // 0..4095
    int ttile = bidx & 3;
    int s     = (bidx >> 2) & 511;
    int b     = bidx >> 11;
    int tid   = threadIdx.x;

    { const float4* src = (const float4*)ew2p;
      float4* dst = (float4*)ew2s;
      for (int i = tid; i < 4096; i += 256) dst[i] = src[i]; }
    psp[tid >= 256 ? 0 : tid] = ps[((b * 512 + s) << 8) + (tid & 255)] + eb1[tid & 255];
    if (tid < 128) eb2s[tid] = eb2[tid];
    ew3s[tid] = ew3[tid];
    __syncthreads();

    int w = tid >> 6, lane = tid & 63;
    int lrow = lane & 15, lg = lane >> 4;
    int t0 = ttile * 128 + w * 32;
    const float* ptb = pt + ((size_t)b * 512) * 256;

    f32x4 acc[2][8];
    #pragma unroll
    for (int m = 0; m < 2; ++m)
        #pragma unroll
        for (int n = 0; n < 8; ++n) acc[m][n] = (f32x4){0.f, 0.f, 0.f, 0.f};

    #pragma unroll
    for (int kk = 0; kk < 8; ++kk) {
        int ks = kk * 32 + lg * 8;
        short8 af[2];
        #pragma unroll
        for (int m = 0; m < 2; ++m) {
            int t = t0 + m * 16 + lrow;
            const float4* pv = (const float4*)(ptb + (size_t)t * 256 + ks);
            float4 v0 = pv[0], v1 = pv[1];
            const float4* pp = (const float4*)(psp + ks);
            float4 p0 = pp[0], p1 = pp[1];
            short8 a;
            a[0] = f2bf(fmaxf(v0.x + p0.x, 0.f));
            a[1] = f2bf(fmaxf(v0.y + p0.y, 0.f));
            a[2] = f2bf(fmaxf(v0.z + p0.z, 0.f));
            a[3] = f2bf(fmaxf(v0.w + p0.w, 0.f));
            a[4] = f2bf(fmaxf(v1.x + p1.x, 0.f));
            a[5] = f2bf(fmaxf(v1.y + p1.y, 0.f));
            a[6] = f2bf(fmaxf(v1.z + p1.z, 0.f));
            a[7] = f2bf(fmaxf(v1.w + p1.w, 0.f));
            af[m] = a;
        }
        #pragma unroll
        for (int n = 0; n < 8; ++n) {
            short8 bf = *(const short8*)(ew2s + (((kk * 8 + n) * 64 + lane) << 3));
            acc[0][n] = __builtin_amdgcn_mfma_f32_16x16x32_bf16(af[0], bf, acc[0][n], 0, 0, 0);
            acc[1][n] = __builtin_amdgcn_mfma_f32_16x16x32_bf16(af[1], bf, acc[1][n], 0, 0, 0);
        }
    }

    float e30 = eb3[0], e31 = eb3[1];
    float* crb = cr + ((size_t)(b * 512 + s)) * 512;
    float* cib = ci + ((size_t)(b * 512 + s)) * 512;
    #pragma unroll
    for (int m = 0; m < 2; ++m) {
        #pragma unroll
        for (int r = 0; r < 4; ++r) {
            float p0 = 0.f, p1 = 0.f;
            #pragma unroll
            for (int nf = 0; nf < 8; ++nf) {
                int c = nf * 16 + lrow;
                float h = fmaxf(acc[m][nf][r] + eb2s[c], 0.f);
                p0 += h * ew3s[2 * c];
                p1 += h * ew3s[2 * c + 1];
            }
            #pragma unroll
            for (int msk = 1; msk < 16; msk <<= 1) {
                p0 += __shfl_xor(p0, msk);
                p1 += __shfl_xor(p1, msk);
            }
            if (lrow == 0) {
                int t = t0 + m * 16 + lg * 4 + r;
                crb[t] = p0 + e30;
                cib[t] = p1 + e31;
            }
        }
    }
}

// ---------------------------------------------------------------- ifft stage 1: over t (last axis), in-place
__global__ __launch_bounds__(512) void ifft_t_kernel(float* __restrict__ cr, float* __restrict__ ci,
                                                     const float* __restrict__ tab512)
{
    __shared__ float  rr[512], ri[512];
    __shared__ float2 tw[512];
    int bs = blockIdx.x;                 // b*512 + s
    int tid = threadIdx.x;
    rr[tid] = cr[(size_t)bs * 512 + tid];
    ri[tid] = ci[(size_t)bs * 512 + tid];
    tw[tid] = ((const float2*)tab512)[tid];
    __syncthreads();
    int q = tid;
    float ar = 0.f, ai = 0.f;
    int idx = 0;
    for (int t = 0; t < 512; ++t) {
        float x = rr[t], y = ri[t];
        float2 cs = tw[idx];             // e^{+2pi i q t / 512}
        ar += x * cs.x - y * cs.y;
        ai += x * cs.y + y * cs.x;
        idx = (idx + q) & 511;
    }
    cr[(size_t)bs * 512 + q] = ar;
    ci[(size_t)bs * 512 + q] = ai;
}

// ---------------------------------------------------------------- ifft stage 2: over s, fused scale/sigmoid/output
__global__ __launch_bounds__(512) void ifft_s_kernel(const float* __restrict__ Dr, const float* __restrict__ Di,
                                                     const float* __restrict__ tab512,
                                                     const float* __restrict__ alpha, const float* __restrict__ beta,
                                                     float* __restrict__ out)
{
    __shared__ float2 tw[512];
    int tid = threadIdx.x;
    tw[tid] = ((const float2*)tab512)[tid];
    __syncthreads();
    int b  = blockIdx.x >> 7;            // 256 blocks: b x 128 p-tiles (4 p each)
    int p0 = (blockIdx.x & 127) * 4;
    int q  = tid;
    const float* drb = Dr + ((size_t)b * 512) * 512 + q;
    const float* dib = Di + ((size_t)b * 512) * 512 + q;
    float a0 = 0.f, a1 = 0.f, a2 = 0.f, a3 = 0.f;
    int i0 = 0, i1 = 0, i2 = 0, i3 = 0;
    for (int s = 0; s < 512; ++s) {
        float dr = drb[(size_t)s * 512];
        float di = dib[(size_t)s * 512];
        float2 c0 = tw[i0], c1 = tw[i1], c2 = tw[i2], c3 = tw[i3];
        a0 += dr * c0.x - di * c0.y;
        a1 += dr * c1.x - di * c1.y;
        a2 += dr * c2.x - di * c2.y;
        a3 += dr * c3.x - di * c3.y;
        i0 = (i0 + p0) & 511;
        i1 = (i1 + p0 + 1) & 511;
        i2 = (i2 + p0 + 2) & 511;
        i3 = (i3 + p0 + 3) & 511;
    }
    float al = alpha[0], be = beta[0];
    const float scale = 1.0f / (512.0f * 512.0f);
    size_t base = ((size_t)b * 512 + p0) * 512 + q;
    float l;
    l = al * (a0 * scale) + be; out[base          ] = l; out[524288 + base          ] = 1.f / (1.f + expf(-l));
    l = al * (a1 * scale) + be; out[base +     512] = l; out[524288 + base +     512] = 1.f / (1.f + expf(-l));
    l = al * (a2 * scale) + be; out[base + 2 * 512] = l; out[524288 + base + 2 * 512] = 1.f / (1.f + expf(-l));
    l = al * (a3 * scale) + be; out[base + 3 * 512] = l; out[524288 + base + 3 * 512] = 1.f / (1.f + expf(-l));
}

// ---------------------------------------------------------------- launch
extern "C" void kernel_launch(void* const* d_in, const int* in_sizes, int n_in,
                              void* d_out, int out_size, void* d_ws, size_t ws_size,
                              hipStream_t stream)
{
    const float* spikes = (const float*)d_in[0];
    const float* Wr  = (const float*)d_in[1];
    const float* Wi  = (const float*)d_in[2];
    const float* pw1 = (const float*)d_in[3];
    const float* pb1 = (const float*)d_in[4];
    const float* pw2 = (const float*)d_in[5];
    const float* pb2 = (const float*)d_in[6];
    const float* nw1 = (const float*)d_in[7];
    const float* nb1 = (const float*)d_in[8];
    const float* nw2 = (const float*)d_in[9];
    const float* nb2 = (const float*)d_in[10];
    const float* sw  = (const float*)d_in[11];
    const float* sb  = (const float*)d_in[12];
    const float* tw_ = (const float*)d_in[13];
    const float* tb  = (const float*)d_in[14];
    const float* ew1 = (const float*)d_in[15];
    const float* eb1 = (const float*)d_in[16];
    const float* ew2 = (const float*)d_in[17];
    const float* eb2 = (const float*)d_in[18];
    const float* ew3 = (const float*)d_in[19];
    const float* eb3 = (const float*)d_in[20];
    const float* alpha = (const float*)d_in[21];
    const float* beta  = (const float*)d_in[22];
    float* out = (float*)d_out;
    float* ws  = (float*)d_ws;

    float* TAB4096 = ws + 0;         // 8192 floats (cos,sin interleaved)
    float* TAB512  = ws + 8192;      // 1024
    float* XR   = ws + 9216;         // 1024*32
    float* XI   = ws + 41984;        // 1024*32
    float* BUFA = ws + 74752;        // 1024*128
    float* BUFB = ws + 205824;       // 1024*128
    float* HS   = ws + 336896;       // 1024*256  (hs -> ps in place)
    float* HT   = ws + 599040;       // 1024*256  (ht -> pt in place)
    short* EW2P = (short*)(ws + 861184);   // 32768 shorts
    float* CR   = ws + 877568;       // 2*512*512 (coeffs -> Dr in place)
    float* CI   = ws + 1401856;      // 2*512*512

    tab_init<<<16, 256, 0, stream>>>(TAB4096, TAB512);
    dft_time_kernel<<<1024, 256, 0, stream>>>(spikes, TAB4096, XR, XI);
    energy_kernel<<<1024, 128, 0, stream>>>(XR, XI, Wr, Wi, BUFA);
    lin_kernel<128, 128, true ><<<1024, 128, 0, stream>>>(BUFA, pw1, pb1, BUFB);
    lin_kernel<128, 128, false><<<1024, 128, 0, stream>>>(BUFB, pw2, pb2, BUFA);
    lin_kernel<128, 128, true ><<<1024, 128, 0, stream>>>(BUFA, nw1, nb1, BUFB);
    lin_kernel<128, 128, true ><<<1024, 128, 0, stream>>>(BUFB, nw2, nb2, BUFA);   // H
    lin_kernel<128, 256, false><<<1024, 256, 0, stream>>>(BUFA, sw, sb, HS);       // hs
    lin_kernel<128, 256, false><<<1024, 256, 0, stream>>>(BUFA, tw_, tb, HT);      // ht
    lin_kernel<256, 256, false><<<1024, 256, 0, stream>>>(HS, ew1, nullptr, HS);           // ps
    lin_kernel<256, 256, false><<<1024, 256, 0, stream>>>(HT, ew1 + 256 * 256, nullptr, HT); // pt
    pack_ew2<<<128, 256, 0, stream>>>(ew2, EW2P);
    edge_mfma<<<4096, 256, 0, stream>>>(HS, HT, eb1, EW2P, eb2, ew3, eb3, CR, CI);
    ifft_t_kernel<<<1024, 512, 0, stream>>>(CR, CI, TAB512);
    ifft_s_kernel<<<256, 512, 0, stream>>>(CR, CI, TAB512, alpha, beta, out);
}

// Round 3
// 207.196 us; speedup vs baseline: 1.7314x; 1.7314x over previous
//
#include <hip/hip_runtime.h>
#include <hip/hip_bf16.h>
#include <math.h>

typedef __attribute__((ext_vector_type(8))) short short8;
typedef __attribute__((ext_vector_type(4))) float f32x4;

__device__ __forceinline__ short f2bf(float x) {
    union { float f; unsigned u; } v; v.f = x;
    unsigned r = v.u + 0x7fffu + ((v.u >> 16) & 1u);   // RNE
    return (short)(r >> 16);
}
__device__ __forceinline__ unsigned cvtpk(float lo, float hi) {
    unsigned r;
    asm("v_cvt_pk_bf16_f32 %0, %1, %2" : "=v"(r) : "v"(lo), "v"(hi));
    return r;   // lo16 = bf16(lo), hi16 = bf16(hi)
}
union U32x4 { unsigned u[4]; short8 s8; };

// ================================================================ tables
// W4P: packed B-frags for temporal DFT  [kkg 128][nf 4][lane 64][j 8]   (262144 bf16)
// F1P: packed B-frags for ifft stage 1  [kk 32][nfg 64][lane 64][j 8]   (1048576 bf16)
// F2 : row-major A for ifft stage 2     [p 512][k2 1024]                (524288 bf16)
__global__ __launch_bounds__(256) void tabs_kernel(short* __restrict__ W4P,
                                                   short* __restrict__ F1P,
                                                   short* __restrict__ F2) {
    int i = blockIdx.x * 256 + threadIdx.x;
    if (i < 262144) {
        int j = i & 7, lane = (i >> 3) & 63, nf = (i >> 9) & 3, kkg = i >> 11;
        int k = kkg * 32 + (lane >> 4) * 8 + j;        // t index 0..4095
        int n = nf * 16 + (lane & 15);                 // 0..63
        int ph = (k * (n & 31)) & 4095;
        float sn, cs; sincospif((float)ph * (1.0f / 2048.0f), &sn, &cs);
        W4P[i] = f2bf(n < 32 ? cs : -sn);
    } else if (i < 262144 + 1048576) {
        int ii = i - 262144;
        int j = ii & 7, lane = (ii >> 3) & 63, nfg = (ii >> 9) & 63, kk = ii >> 15;
        int k2 = kk * 32 + (lane >> 4) * 8 + j;        // 2t + c
        int t = k2 >> 1, c = k2 & 1;
        int n = nfg * 16 + (lane & 15);                // 2q + d
        int q = n >> 1, d = n & 1;
        int ph = (t * q) & 511;
        float sn, cs; sincospif((float)ph * (1.0f / 256.0f), &sn, &cs);
        float val = (c == d) ? cs : (c ? -sn : sn);
        F1P[ii] = f2bf(val);
    } else if (i < 262144 + 1048576 + 524288) {
        int ii = i - (262144 + 1048576);
        int p = ii >> 10, k2 = ii & 1023;
        int s = k2 >> 1, dd = k2 & 1;
        int ph = (p * s) & 511;
        float sn, cs; sincospif((float)ph * (1.0f / 256.0f), &sn, &cs);
        F2[ii] = f2bf(dd ? -sn : cs);
    }
}

// ---------------------------------------------------------------- pack ew2 [256x128] -> bf16 B-frag order
__global__ void pack_ew2(const float* __restrict__ ew2, short* __restrict__ out) {
    int i = blockIdx.x * 256 + threadIdx.x;     // 32768
    int j = i & 7, lane = (i >> 3) & 63, nf = (i >> 9) & 7, kk = i >> 12;
    int k = kk * 32 + (lane >> 4) * 8 + j;
    int n = nf * 16 + (lane & 15);
    out[i] = f2bf(ew2[k * 128 + n]);
}

// ================================================================ temporal DFT via MFMA
// out X64[row 1024][64]: cols 0..31 = Xr, 32..63 = Xi
__global__ __launch_bounds__(256) void dft_mfma(const float* __restrict__ spikes,
                                                const short* __restrict__ W4P,
                                                float* __restrict__ X64) {
    __shared__ float red[4][4][64][4];   // wave, nf, lane, r
    int row0 = blockIdx.x * 16;
    int tid = threadIdx.x, wid = tid >> 6, lane = tid & 63;
    int lrow = lane & 15, lg = lane >> 4;

    f32x4 acc[4];
    #pragma unroll
    for (int n = 0; n < 4; ++n) acc[n] = (f32x4){0.f, 0.f, 0.f, 0.f};

    int row = row0 + lrow;
    const float* sbase = spikes + (size_t)row * 4096;
    #pragma unroll 4
    for (int kk = 0; kk < 32; ++kk) {
        int k = wid * 1024 + kk * 32 + lg * 8;
        const float4* sp = (const float4*)(sbase + k);
        float4 v0 = sp[0], v1 = sp[1];
        U32x4 a;
        a.u[0] = cvtpk(v0.x, v0.y);
        a.u[1] = cvtpk(v0.z, v0.w);
        a.u[2] = cvtpk(v1.x, v1.y);
        a.u[3] = cvtpk(v1.z, v1.w);
        int kkg = (wid * 1024 + kk * 32) >> 5;
        #pragma unroll
        for (int n = 0; n < 4; ++n) {
            short8 bfr = *(const short8*)(W4P + ((kkg * 4 + n) * 64 + lane) * 8);
            acc[n] = __builtin_amdgcn_mfma_f32_16x16x32_bf16(a.s8, bfr, acc[n], 0, 0, 0);
        }
    }
    #pragma unroll
    for (int n = 0; n < 4; ++n)
        #pragma unroll
        for (int r = 0; r < 4; ++r) red[wid][n][lane][r] = acc[n][r];
    __syncthreads();
    // wave wid reduces nf = wid
    #pragma unroll
    for (int r = 0; r < 4; ++r) {
        float s = red[0][wid][lane][r] + red[1][wid][lane][r]
                + red[2][wid][lane][r] + red[3][wid][lane][r];
        int orow = row0 + lg * 4 + r;
        X64[(size_t)orow * 64 + wid * 16 + lrow] = s;
    }
}

// ---------------------------------------------------------------- mode-energy
__global__ __launch_bounds__(128) void energy_kernel(const float* __restrict__ X64,
                                                     const float* __restrict__ Wr, const float* __restrict__ Wi,
                                                     float* __restrict__ E) {
    __shared__ float sxr[32], sxi[32];
    int row = blockIdx.x, tid = threadIdx.x;
    if (tid < 32) { sxr[tid] = X64[row * 64 + tid]; sxi[tid] = X64[row * 64 + 32 + tid]; }
    __syncthreads();
    float acc = 0.f;
    #pragma unroll 8
    for (int k = 0; k < 32; ++k) {
        float a = sxr[k], b = sxi[k];
        float wr = Wr[k * 128 + tid], wi = Wi[k * 128 + tid];
        float yr = a * wr - b * wi;
        float yi = a * wi + b * wr;
        acc += sqrtf(yr * yr + yi * yi + 1e-8f);
    }
    E[row * 128 + tid] = acc * (1.0f / 32.0f);
}

// ---------------------------------------------------------------- fused 2-layer 128->128->128, 4 rows/block
template<bool RELU2>
__global__ __launch_bounds__(128) void k_2lin(const float* __restrict__ A,
                                              const float* __restrict__ W1, const float* __restrict__ b1,
                                              const float* __restrict__ W2, const float* __restrict__ b2,
                                              float* __restrict__ C) {
    __shared__ float in[4][128], mid[4][128];
    int r0 = blockIdx.x * 4, tid = threadIdx.x;
    #pragma unroll
    for (int r = 0; r < 4; ++r) in[r][tid] = A[(size_t)(r0 + r) * 128 + tid];
    __syncthreads();
    float acc[4] = {b1[tid], b1[tid], b1[tid], b1[tid]};
    #pragma unroll 8
    for (int i = 0; i < 128; ++i) {
        float w = W1[i * 128 + tid];
        #pragma unroll
        for (int r = 0; r < 4; ++r) acc[r] += in[r][i] * w;
    }
    #pragma unroll
    for (int r = 0; r < 4; ++r) mid[r][tid] = fmaxf(acc[r], 0.f);
    __syncthreads();
    float acc2[4] = {b2[tid], b2[tid], b2[tid], b2[tid]};
    #pragma unroll 8
    for (int i = 0; i < 128; ++i) {
        float w = W2[i * 128 + tid];
        #pragma unroll
        for (int r = 0; r < 4; ++r) acc2[r] += mid[r][i] * w;
    }
    #pragma unroll
    for (int r = 0; r < 4; ++r)
        C[(size_t)(r0 + r) * 128 + tid] = RELU2 ? fmaxf(acc2[r], 0.f) : acc2[r];
}

// ---------------------------------------------------------------- H -> hs, ht  (K=128, N=256 each)
__global__ __launch_bounds__(256) void k_st(const float* __restrict__ H,
                                            const float* __restrict__ sw, const float* __restrict__ sb,
                                            const float* __restrict__ tw, const float* __restrict__ tb,
                                            float* __restrict__ hs, float* __restrict__ ht) {
    __shared__ float in[4][128];
    int r0 = blockIdx.x * 4, tid = threadIdx.x;
    if (tid < 128) {
        #pragma unroll
        for (int r = 0; r < 4; ++r) in[r][tid] = H[(size_t)(r0 + r) * 128 + tid];
    }
    __syncthreads();
    float as[4] = {sb[tid], sb[tid], sb[tid], sb[tid]};
    float at[4] = {tb[tid], tb[tid], tb[tid], tb[tid]};
    #pragma unroll 8
    for (int i = 0; i < 128; ++i) {
        float wsv = sw[i * 256 + tid];
        float wtv = tw[i * 256 + tid];
        #pragma unroll
        for (int r = 0; r < 4; ++r) { as[r] += in[r][i] * wsv; at[r] += in[r][i] * wtv; }
    }
    #pragma unroll
    for (int r = 0; r < 4; ++r) {
        hs[(size_t)(r0 + r) * 256 + tid] = as[r];
        ht[(size_t)(r0 + r) * 256 + tid] = at[r];
    }
}

// ---------------------------------------------------------------- hs,ht -> ps, pt  (K=256, N=256 each)
__global__ __launch_bounds__(256) void k_pspt(const float* __restrict__ hs, const float* __restrict__ ht,
                                              const float* __restrict__ ew1,
                                              float* __restrict__ ps, float* __restrict__ pt) {
    __shared__ float ins[4][256], int_[4][256];
    int r0 = blockIdx.x * 4, tid = threadIdx.x;
    #pragma unroll
    for (int r = 0; r < 4; ++r) {
        ins[r][tid] = hs[(size_t)(r0 + r) * 256 + tid];
        int_[r][tid] = ht[(size_t)(r0 + r) * 256 + tid];
    }
    __syncthreads();
    float aa[4] = {0.f, 0.f, 0.f, 0.f};
    float ab[4] = {0.f, 0.f, 0.f, 0.f};
    #pragma unroll 4
    for (int i = 0; i < 256; ++i) {
        float wa = ew1[i * 256 + tid];
        float wb = ew1[(256 + i) * 256 + tid];
        #pragma unroll
        for (int r = 0; r < 4; ++r) { aa[r] += ins[r][i] * wa; ab[r] += int_[r][i] * wb; }
    }
    #pragma unroll
    for (int r = 0; r < 4; ++r) {
        ps[(size_t)(r0 + r) * 256 + tid] = aa[r];
        pt[(size_t)(r0 + r) * 256 + tid] = ab[r];
    }
}

// ================================================================ edge MLP v2: 16 s x 64 t per block
// writes coeffs CC[bs][2t+c] bf16 (interleaved cr,ci) = A-matrix of ifft stage 1
__global__ __launch_bounds__(512) void edge_mfma2(
    const float* __restrict__ ps, const float* __restrict__ pt,
    const float* __restrict__ eb1, const short* __restrict__ ew2p,
    const float* __restrict__ eb2, const float* __restrict__ ew3,
    const float* __restrict__ eb3, short* __restrict__ CC) {
    __shared__ __align__(16) short ew2s[32768];      // 64 KB
    __shared__ __align__(16) float pts[64 * 256];    // 64 KB, float4-XOR-swizzled
    __shared__ __align__(16) float pss[16 * 256];    // 16 KB, ps + eb1
    __shared__ float eb2s[128];
    __shared__ float ew3s[256];

    int bidx = blockIdx.x;                 // 512 blocks
    int ttile = bidx & 7;
    int stile = (bidx >> 3) & 31;
    int b = bidx >> 8;
    int s0 = stile * 16, t0 = ttile * 64;
    int tid = threadIdx.x;

    // stage ew2 fragments (32768 shorts = 4096 float4)
    { const float4* src = (const float4*)ew2p;
      float4* dst = (float4*)ew2s;
      #pragma unroll
      for (int it = 0; it < 8; ++it) dst[tid + it * 512] = src[tid + it * 512]; }
    // stage pt tile (swizzled float4)
    { const float4* src = (const float4*)(pt + ((size_t)(b * 512 + t0)) * 256);
      float4* dst = (float4*)pts;
      #pragma unroll
      for (int it = 0; it < 8; ++it) {
          int idx = tid + it * 512;                  // 4096 float4
          int tl = idx >> 6, f = idx & 63;
          dst[tl * 64 + (f ^ (tl & 7))] = src[idx];
      } }
    // stage ps + eb1
    { const float4* src = (const float4*)(ps + ((size_t)(b * 512 + s0)) * 256);
      const float4* be = (const float4*)eb1;
      float4* dst = (float4*)pss;
      #pragma unroll
      for (int it = 0; it < 2; ++it) {
          int idx = tid + it * 512;                  // 1024 float4
          float4 v = src[idx], e = be[idx & 63];
          v.x += e.x; v.y += e.y; v.z += e.z; v.w += e.w;
          dst[idx] = v;
      } }
    if (tid < 128) eb2s[tid] = eb2[tid];
    if (tid < 256) ew3s[tid] = ew3[tid];
    __syncthreads();

    int wid = tid >> 6, lane = tid & 63;
    int lrow = lane & 15, lg = lane >> 4;
    float e30 = eb3[0], e31 = eb3[1];
    const float4* pts4 = (const float4*)pts;
    const float4* pss4 = (const float4*)pss;
    unsigned* CC32 = (unsigned*)CC;

    #pragma unroll 1
    for (int i = 0; i < 8; ++i) {
        int mf = wid * 8 + i;
        int s_local = mf >> 2;
        int tb_ = (mf & 3) * 16;
        int tl = tb_ + lrow;
        int swz = tl & 7;

        f32x4 acc[8];
        #pragma unroll
        for (int n = 0; n < 8; ++n) acc[n] = (f32x4){0.f, 0.f, 0.f, 0.f};

        #pragma unroll
        for (int kk = 0; kk < 8; ++kk) {
            int f0 = kk * 8 + lg * 2;
            float4 pA = pss4[s_local * 64 + f0];
            float4 pB = pss4[s_local * 64 + f0 + 1];
            float4 vA = pts4[tl * 64 + (f0 ^ swz)];
            float4 vB = pts4[tl * 64 + ((f0 + 1) ^ swz)];
            U32x4 a;
            a.u[0] = cvtpk(fmaxf(vA.x + pA.x, 0.f), fmaxf(vA.y + pA.y, 0.f));
            a.u[1] = cvtpk(fmaxf(vA.z + pA.z, 0.f), fmaxf(vA.w + pA.w, 0.f));
            a.u[2] = cvtpk(fmaxf(vB.x + pB.x, 0.f), fmaxf(vB.y + pB.y, 0.f));
            a.u[3] = cvtpk(fmaxf(vB.z + pB.z, 0.f), fmaxf(vB.w + pB.w, 0.f));
            #pragma unroll
            for (int n = 0; n < 8; ++n) {
                short8 bfr = *(const short8*)(ew2s + (((kk * 8 + n) * 64 + lane) << 3));
                acc[n] = __builtin_amdgcn_mfma_f32_16x16x32_bf16(a.s8, bfr, acc[n], 0, 0, 0);
            }
        }

        size_t outrow = (size_t)(b * 512 + s0 + s_local) * 512;
        #pragma unroll
        for (int r = 0; r < 4; ++r) {
            float p0 = 0.f, p1 = 0.f;
            #pragma unroll
            for (int nf = 0; nf < 8; ++nf) {
                int c = nf * 16 + lrow;
                float h = fmaxf(acc[nf][r] + eb2s[c], 0.f);
                p0 += h * ew3s[2 * c];
                p1 += h * ew3s[2 * c + 1];
            }
            #pragma unroll
            for (int msk = 1; msk < 16; msk <<= 1) {
                p0 += __shfl_xor(p0, msk);
                p1 += __shfl_xor(p1, msk);
            }
            if (lrow == 0) {
                int t = t0 + tb_ + lg * 4 + r;
                CC32[outrow + t] = cvtpk(p0 + e30, p1 + e31);
            }
        }
    }
}

// ================================================================ ifft stage 1 (over t), MFMA
// A = CC[bs][2t+c], B = F1P packed; output written B-frag-packed into B2P[b][kk2][nf2][lane][j]
__global__ __launch_bounds__(256) void ifft1_mfma(const short* __restrict__ CC,
                                                  const short* __restrict__ F1P,
                                                  short* __restrict__ B2P) {
    __shared__ short st[32 * 128];   // 8 KB
    int bidx = blockIdx.x;           // 256: mt(64) x nt(4)
    int nt = bidx & 3;
    int mt = bidx >> 2;
    int bs0 = mt * 16;
    int b = mt >> 5;
    int kk2 = mt & 31;
    int tid = threadIdx.x, wid = tid >> 6, lane = tid & 63;
    int lrow = lane & 15, lg = lane >> 4;

    f32x4 acc[4];
    #pragma unroll
    for (int f = 0; f < 4; ++f) acc[f] = (f32x4){0.f, 0.f, 0.f, 0.f};

    const short* arow = CC + (size_t)(bs0 + lrow) * 1024 + lg * 8;
    #pragma unroll 4
    for (int kk = 0; kk < 32; ++kk) {
        short8 a = *(const short8*)(arow + kk * 32);
        #pragma unroll
        for (int f = 0; f < 4; ++f) {
            int nfg = nt * 16 + wid * 4 + f;
            short8 bfr = *(const short8*)(F1P + ((kk * 64 + nfg) * 64 + lane) * 8);
            acc[f] = __builtin_amdgcn_mfma_f32_16x16x32_bf16(a, bfr, acc[f], 0, 0, 0);
        }
    }
    #pragma unroll
    for (int f = 0; f < 4; ++f)
        #pragma unroll
        for (int r = 0; r < 4; ++r) {
            int n_local = (wid * 4 + f) * 16 + lrow;    // 0..255
            int lq = n_local >> 1, d = n_local & 1;
            int lk = (lg * 4 + r) * 2 + d;              // 0..31
            st[lk * 128 + lq] = f2bf(acc[f][r]);
        }
    __syncthreads();
    #pragma unroll
    for (int half = 0; half < 2; ++half) {
        int f2 = (tid >> 6) + half * 4;                 // 0..7
        int nf2 = nt * 8 + f2;
        short8 v;
        #pragma unroll
        for (int j = 0; j < 8; ++j)
            v[j] = st[((lane >> 4) * 8 + j) * 128 + f2 * 16 + (lane & 15)];
        *(short8*)(B2P + (size_t)b * 524288 + ((size_t)(kk2 * 32 + nf2) * 64 + lane) * 8) = v;
    }
}

// ================================================================ ifft stage 2 (over s) + scale/sigmoid
__global__ __launch_bounds__(256) void ifft2_mfma(const short* __restrict__ B2P,
                                                  const short* __restrict__ F2,
                                                  const float* __restrict__ alpha, const float* __restrict__ beta,
                                                  float* __restrict__ out) {
    int bidx = blockIdx.x;           // 256: p-tile(32) x qt(4) x b(2)
    int pt_ = bidx & 31;
    int qt = (bidx >> 5) & 3;
    int b = bidx >> 7;
    int p0 = pt_ * 16;
    int tid = threadIdx.x, wid = tid >> 6, lane = tid & 63;
    int lrow = lane & 15, lg = lane >> 4;

    f32x4 acc[2];
    acc[0] = (f32x4){0.f, 0.f, 0.f, 0.f};
    acc[1] = (f32x4){0.f, 0.f, 0.f, 0.f};

    const short* arow = F2 + (size_t)(p0 + lrow) * 1024 + lg * 8;
    const short* bbase = B2P + (size_t)b * 524288;
    #pragma unroll 4
    for (int kk = 0; kk < 32; ++kk) {
        short8 a = *(const short8*)(arow + kk * 32);
        #pragma unroll
        for (int f = 0; f < 2; ++f) {
            int nfg = qt * 8 + wid * 2 + f;
            short8 bfr = *(const short8*)(bbase + ((size_t)(kk * 32 + nfg) * 64 + lane) * 8);
            acc[f] = __builtin_amdgcn_mfma_f32_16x16x32_bf16(a, bfr, acc[f], 0, 0, 0);
        }
    }
    float al = alpha[0], be = beta[0];
    const float scale = 1.0f / (512.0f * 512.0f);
    #pragma unroll
    for (int f = 0; f < 2; ++f)
        #pragma unroll
        for (int r = 0; r < 4; ++r) {
            int q = qt * 128 + (wid * 2 + f) * 16 + lrow;
            int p = p0 + lg * 4 + r;
            float l = al * (acc[f][r] * scale) + be;
            size_t idx = (size_t)b * 262144 + (size_t)p * 512 + q;
            out[idx] = l;
            out[524288 + idx] = 1.f / (1.f + expf(-l));
        }
}

// ================================================================ launch
extern "C" void kernel_launch(void* const* d_in, const int* in_sizes, int n_in,
                              void* d_out, int out_size, void* d_ws, size_t ws_size,
                              hipStream_t stream) {
    const float* spikes = (const float*)d_in[0];
    const float* Wr  = (const float*)d_in[1];
    const float* Wi  = (const float*)d_in[2];
    const float* pw1 = (const float*)d_in[3];
    const float* pb1 = (const float*)d_in[4];
    const float* pw2 = (const float*)d_in[5];
    const float* pb2 = (const float*)d_in[6];
    const float* nw1 = (const float*)d_in[7];
    const float* nb1 = (const float*)d_in[8];
    const float* nw2 = (const float*)d_in[9];
    const float* nb2 = (const float*)d_in[10];
    const float* sw  = (const float*)d_in[11];
    const float* sb  = (const float*)d_in[12];
    const float* tw_ = (const float*)d_in[13];
    const float* tb  = (const float*)d_in[14];
    const float* ew1 = (const float*)d_in[15];
    const float* eb1 = (const float*)d_in[16];
    const float* ew2 = (const float*)d_in[17];
    const float* eb2 = (const float*)d_in[18];
    const float* ew3 = (const float*)d_in[19];
    const float* eb3 = (const float*)d_in[20];
    const float* alpha = (const float*)d_in[21];
    const float* beta  = (const float*)d_in[22];
    float* out = (float*)d_out;
    float* ws  = (float*)d_ws;

    float* BUFA = ws + 0;            // 131072  (E, later H)
    float* BUFB = ws + 131072;       // 131072  (X64 in first 65536, later P)
    float* HS   = ws + 262144;       // 262144
    float* HT   = ws + 524288;       // 262144
    float* PS   = ws + 786432;       // 262144
    float* PT   = ws + 1048576;      // 262144
    short* EW2P = (short*)(ws + 1310720);   // 32768 shorts
    short* W4P  = (short*)(ws + 1327104);   // 262144 shorts
    short* F1P  = (short*)(ws + 1458176);   // 1048576 shorts
    short* F2   = (short*)(ws + 1982464);   // 524288 shorts
    short* CC   = (short*)(ws + 262144);    // overlays HS/HT (1048576 shorts)
    short* B2P  = (short*)(ws + 786432);    // overlays PS/PT (1048576 shorts)
    float* X64  = BUFB;

    tabs_kernel<<<7168, 256, 0, stream>>>(W4P, F1P, F2);
    pack_ew2<<<128, 256, 0, stream>>>(ew2, EW2P);
    dft_mfma<<<64, 256, 0, stream>>>(spikes, W4P, X64);
    energy_kernel<<<1024, 128, 0, stream>>>(X64, Wr, Wi, BUFA);
    k_2lin<false><<<256, 128, 0, stream>>>(BUFA, pw1, pb1, pw2, pb2, BUFB);   // E -> P
    k_2lin<true ><<<256, 128, 0, stream>>>(BUFB, nw1, nb1, nw2, nb2, BUFA);   // P -> H
    k_st<<<256, 256, 0, stream>>>(BUFA, sw, sb, tw_, tb, HS, HT);
    k_pspt<<<256, 256, 0, stream>>>(HS, HT, ew1, PS, PT);
    edge_mfma2<<<512, 512, 0, stream>>>(PS, PT, eb1, EW2P, eb2, ew3, eb3, CC);
    ifft1_mfma<<<256, 256, 0, stream>>>(CC, F1P, B2P);
    ifft2_mfma<<<256, 256, 0, stream>>>(B2P, F2, alpha, beta, out);
}

// Round 4
// 154.022 us; speedup vs baseline: 2.3292x; 1.3452x over previous
//
#include <hip/hip_runtime.h>
#include <hip/hip_bf16.h>
#include <math.h>

typedef __attribute__((ext_vector_type(8))) short short8;
typedef __attribute__((ext_vector_type(4))) float f32x4;

__device__ __forceinline__ short f2bf(float x) {
    union { float f; unsigned u; } v; v.f = x;
    unsigned r = v.u + 0x7fffu + ((v.u >> 16) & 1u);   // RNE
    return (short)(r >> 16);
}
__device__ __forceinline__ unsigned cvtpk(float lo, float hi) {
    unsigned r;
    asm("v_cvt_pk_bf16_f32 %0, %1, %2" : "=v"(r) : "v"(lo), "v"(hi));
    return r;   // lo16 = bf16(lo), hi16 = bf16(hi)
}
union U32x4 { unsigned u[4]; short8 s8; };

// ================================================================ setup: all tables + weight packing
// W4P : packed B-frags, temporal DFT  [kkg 128][nf 4][lane 64][j 8]   262144 bf16
// F1P : packed B-frags, ifft stage 1  [kk 32][nfg 64][lane 64][j 8]   1048576 bf16
// F2  : row-major A, ifft stage 2     [p 512][k2 1024]                524288 bf16
// EW2T: packed A-frags, edge layer2   [kk 8][hf 8][lane 64][j 8]      32768 bf16
__global__ __launch_bounds__(256) void setup_kernel(const float* __restrict__ ew2,
                                                    short* __restrict__ W4P,
                                                    short* __restrict__ F1P,
                                                    short* __restrict__ F2,
                                                    short* __restrict__ EW2T) {
    int i = blockIdx.x * 256 + threadIdx.x;
    if (i < 262144) {
        int j = i & 7, lane = (i >> 3) & 63, nf = (i >> 9) & 3, kkg = i >> 11;
        int k = kkg * 32 + (lane >> 4) * 8 + j;        // t index 0..4095
        int n = nf * 16 + (lane & 15);                 // 0..63
        int ph = (k * (n & 31)) & 4095;
        float sn, cs; sincospif((float)ph * (1.0f / 2048.0f), &sn, &cs);
        W4P[i] = f2bf(n < 32 ? cs : -sn);
    } else if (i < 1310720) {
        int ii = i - 262144;
        int j = ii & 7, lane = (ii >> 3) & 63, nfg = (ii >> 9) & 63, kk = ii >> 15;
        int k2 = kk * 32 + (lane >> 4) * 8 + j;        // 2t + c
        int t = k2 >> 1, c = k2 & 1;
        int n = nfg * 16 + (lane & 15);                // 2q + d
        int q = n >> 1, d = n & 1;
        int ph = (t * q) & 511;
        float sn, cs; sincospif((float)ph * (1.0f / 256.0f), &sn, &cs);
        float val = (c == d) ? cs : (c ? -sn : sn);
        F1P[ii] = f2bf(val);
    } else if (i < 1835008) {
        int ii = i - 1310720;
        int p = ii >> 10, k2 = ii & 1023;
        int s = k2 >> 1, dd = k2 & 1;
        int ph = (p * s) & 511;
        float sn, cs; sincospif((float)ph * (1.0f / 256.0f), &sn, &cs);
        F2[ii] = f2bf(dd ? -sn : cs);
    } else if (i < 1867776) {
        int ii = i - 1835008;
        int j = ii & 7, lane = (ii >> 3) & 63, hf = (ii >> 9) & 7, kk = ii >> 12;
        int k = kk * 32 + (lane >> 4) * 8 + j;         // 0..255
        int h = hf * 16 + (lane & 15);                 // 0..127
        EW2T[ii] = f2bf(ew2[k * 128 + h]);
    }
}

// ================================================================ temporal DFT via MFMA, split-k x4
// X64P[part 4][row 1024][64]: cols 0..31 = Xr, 32..63 = Xi (partial sums)
__global__ __launch_bounds__(256) void dft_mfma(const float* __restrict__ spikes,
                                                const short* __restrict__ W4P,
                                                float* __restrict__ X64P) {
    __shared__ float red[4][4][64][4];   // wave, nf, lane, r
    int part = blockIdx.x & 3;
    int row0 = (blockIdx.x >> 2) * 16;
    int tid = threadIdx.x, wid = tid >> 6, lane = tid & 63;
    int lrow = lane & 15, lg = lane >> 4;

    f32x4 acc[4];
    #pragma unroll
    for (int n = 0; n < 4; ++n) acc[n] = (f32x4){0.f, 0.f, 0.f, 0.f};

    int row = row0 + lrow;
    const float* sbase = spikes + (size_t)row * 4096;
    #pragma unroll
    for (int kk = 0; kk < 8; ++kk) {
        int k = part * 1024 + wid * 256 + kk * 32 + lg * 8;
        const float4* sp = (const float4*)(sbase + k);
        float4 v0 = sp[0], v1 = sp[1];
        U32x4 a;
        a.u[0] = cvtpk(v0.x, v0.y);
        a.u[1] = cvtpk(v0.z, v0.w);
        a.u[2] = cvtpk(v1.x, v1.y);
        a.u[3] = cvtpk(v1.z, v1.w);
        int kkg = part * 32 + wid * 8 + kk;
        #pragma unroll
        for (int n = 0; n < 4; ++n) {
            short8 bfr = *(const short8*)(W4P + ((kkg * 4 + n) * 64 + lane) * 8);
            acc[n] = __builtin_amdgcn_mfma_f32_16x16x32_bf16(a.s8, bfr, acc[n], 0, 0, 0);
        }
    }
    #pragma unroll
    for (int n = 0; n < 4; ++n)
        #pragma unroll
        for (int r = 0; r < 4; ++r) red[wid][n][lane][r] = acc[n][r];
    __syncthreads();
    #pragma unroll
    for (int r = 0; r < 4; ++r) {
        float s = red[0][wid][lane][r] + red[1][wid][lane][r]
                + red[2][wid][lane][r] + red[3][wid][lane][r];
        int orow = row0 + lg * 4 + r;
        X64P[(size_t)part * 65536 + (size_t)orow * 64 + wid * 16 + lrow] = s;
    }
}

// ================================================================ fused node chain: energy + post_mlp + node_net
// 4 rows/block, 128 threads. X64P partials summed here.
__global__ __launch_bounds__(128) void k_node(const float* __restrict__ X64P,
                                              const float* __restrict__ Wr, const float* __restrict__ Wi,
                                              const float* __restrict__ pw1, const float* __restrict__ pb1,
                                              const float* __restrict__ pw2, const float* __restrict__ pb2,
                                              const float* __restrict__ nw1, const float* __restrict__ nb1,
                                              const float* __restrict__ nw2, const float* __restrict__ nb2,
                                              float* __restrict__ H) {
    __shared__ float sx[4][64];
    __shared__ float bufA[4][128], bufB[4][128];
    int r0 = blockIdx.x * 4, tid = threadIdx.x;

    #pragma unroll
    for (int it = 0; it < 2; ++it) {
        int idx = tid + it * 128;              // 256 elems: 4 rows x 64
        int row = idx >> 6, col = idx & 63;
        float v = 0.f;
        #pragma unroll
        for (int p = 0; p < 4; ++p)
            v += X64P[(size_t)p * 65536 + (size_t)(r0 + row) * 64 + col];
        sx[row][col] = v;
    }
    __syncthreads();

    // energy
    float eacc[4] = {0.f, 0.f, 0.f, 0.f};
    #pragma unroll 8
    for (int k = 0; k < 32; ++k) {
        float wr = Wr[k * 128 + tid], wi = Wi[k * 128 + tid];
        #pragma unroll
        for (int r = 0; r < 4; ++r) {
            float a = sx[r][k], b = sx[r][32 + k];
            float yr = a * wr - b * wi;
            float yi = a * wi + b * wr;
            eacc[r] += sqrtf(yr * yr + yi * yi + 1e-8f);
        }
    }
    #pragma unroll
    for (int r = 0; r < 4; ++r) bufA[r][tid] = eacc[r] * (1.0f / 32.0f);
    __syncthreads();

    // L1: relu(E @ pw1 + pb1) -> bufB
    { float acc[4] = {pb1[tid], pb1[tid], pb1[tid], pb1[tid]};
      #pragma unroll 8
      for (int i = 0; i < 128; ++i) { float w = pw1[i * 128 + tid];
          #pragma unroll
          for (int r = 0; r < 4; ++r) acc[r] += bufA[r][i] * w; }
      __syncthreads();
      #pragma unroll
      for (int r = 0; r < 4; ++r) bufB[r][tid] = fmaxf(acc[r], 0.f);
      __syncthreads(); }
    // L2: @ pw2 + pb2 -> bufA
    { float acc[4] = {pb2[tid], pb2[tid], pb2[tid], pb2[tid]};
      #pragma unroll 8
      for (int i = 0; i < 128; ++i) { float w = pw2[i * 128 + tid];
          #pragma unroll
          for (int r = 0; r < 4; ++r) acc[r] += bufB[r][i] * w; }
      __syncthreads();
      #pragma unroll
      for (int r = 0; r < 4; ++r) bufA[r][tid] = acc[r];
      __syncthreads(); }
    // L3: relu(@ nw1 + nb1) -> bufB
    { float acc[4] = {nb1[tid], nb1[tid], nb1[tid], nb1[tid]};
      #pragma unroll 8
      for (int i = 0; i < 128; ++i) { float w = nw1[i * 128 + tid];
          #pragma unroll
          for (int r = 0; r < 4; ++r) acc[r] += bufA[r][i] * w; }
      __syncthreads();
      #pragma unroll
      for (int r = 0; r < 4; ++r) bufB[r][tid] = fmaxf(acc[r], 0.f);
      __syncthreads(); }
    // L4: relu(@ nw2 + nb2) -> H
    { float acc[4] = {nb2[tid], nb2[tid], nb2[tid], nb2[tid]};
      #pragma unroll 8
      for (int i = 0; i < 128; ++i) { float w = nw2[i * 128 + tid];
          #pragma unroll
          for (int r = 0; r < 4; ++r) acc[r] += bufB[r][i] * w; }
      #pragma unroll
      for (int r = 0; r < 4; ++r) H[(size_t)(r0 + r) * 128 + tid] = fmaxf(acc[r], 0.f); }
}

// ================================================================ fused edge-input: hs/ht + ps/pt
__global__ __launch_bounds__(256) void k_edge_in(const float* __restrict__ H,
                                                 const float* __restrict__ sw, const float* __restrict__ sb,
                                                 const float* __restrict__ tw, const float* __restrict__ tb,
                                                 const float* __restrict__ ew1,
                                                 float* __restrict__ PS, float* __restrict__ PT) {
    __shared__ float hin[4][128];
    __shared__ float hst[4][512];      // [row][hs(256) | ht(256)]
    int r0 = blockIdx.x * 4, tid = threadIdx.x;
    #pragma unroll
    for (int it = 0; it < 2; ++it) {
        int idx = tid + it * 256;          // 512: 4 rows x 128
        int row = idx >> 7, col = idx & 127;
        hin[row][col] = H[(size_t)(r0 + row) * 128 + col];
    }
    __syncthreads();
    { float as[4] = {sb[tid], sb[tid], sb[tid], sb[tid]};
      float at[4] = {tb[tid], tb[tid], tb[tid], tb[tid]};
      #pragma unroll 8
      for (int i = 0; i < 128; ++i) {
          float wsv = sw[i * 256 + tid], wtv = tw[i * 256 + tid];
          #pragma unroll
          for (int r = 0; r < 4; ++r) { as[r] += hin[r][i] * wsv; at[r] += hin[r][i] * wtv; }
      }
      #pragma unroll
      for (int r = 0; r < 4; ++r) { hst[r][tid] = as[r]; hst[r][256 + tid] = at[r]; }
      __syncthreads(); }
    { float aa[4] = {0.f, 0.f, 0.f, 0.f}, ab[4] = {0.f, 0.f, 0.f, 0.f};
      #pragma unroll 4
      for (int i = 0; i < 256; ++i) {
          float wa = ew1[i * 256 + tid];
          float wb = ew1[(256 + i) * 256 + tid];
          #pragma unroll
          for (int r = 0; r < 4; ++r) { aa[r] += hst[r][i] * wa; ab[r] += hst[r][256 + i] * wb; }
      }
      #pragma unroll
      for (int r = 0; r < 4; ++r) {
          PS[(size_t)(r0 + r) * 256 + tid] = aa[r];
          PT[(size_t)(r0 + r) * 256 + tid] = ab[r];
      } }
}

// ================================================================ edge MLP v3: swapped operands, 4x B-reuse
// A = ew2^T fragments (h x k), B = relu(ps+pt+eb1) fragments (k x t)
// C: lane&15 = t_local, regs = h -> epilogue reduce needs only 2 shfl rounds
__global__ __launch_bounds__(512, 2) void edge_mfma3(
    const float* __restrict__ ps, const float* __restrict__ pt,
    const float* __restrict__ eb1, const short* __restrict__ ew2t,
    const float* __restrict__ eb2, const float* __restrict__ ew3,
    const float* __restrict__ eb3, short* __restrict__ CC) {
    __shared__ __align__(16) short ew2s[32768];      // 64 KB
    __shared__ __align__(16) float pts[64 * 256];    // 64 KB, float4-XOR-swizzled
    __shared__ __align__(16) float pss[16 * 256];    // 16 KB, ps + eb1
    __shared__ float eb2s[128];
    __shared__ float ew3s[256];

    int bidx = blockIdx.x;                 // 512 blocks
    int ttile = bidx & 7;
    int stile = (bidx >> 3) & 31;
    int b = bidx >> 8;
    int s0 = stile * 16, t0 = ttile * 64;
    int tid = threadIdx.x;

    { const float4* src = (const float4*)ew2t;
      float4* dst = (float4*)ew2s;
      #pragma unroll
      for (int it = 0; it < 8; ++it) dst[tid + it * 512] = src[tid + it * 512]; }
    { const float4* src = (const float4*)(pt + ((size_t)(b * 512 + t0)) * 256);
      float4* dst = (float4*)pts;
      #pragma unroll
      for (int it = 0; it < 8; ++it) {
          int idx = tid + it * 512;                  // 4096 float4
          int tl = idx >> 6, f = idx & 63;
          dst[tl * 64 + (f ^ (tl & 7))] = src[idx];
      } }
    { const float4* src = (const float4*)(ps + ((size_t)(b * 512 + s0)) * 256);
      const float4* be = (const float4*)eb1;
      float4* dst = (float4*)pss;
      #pragma unroll
      for (int it = 0; it < 2; ++it) {
          int idx = tid + it * 512;                  // 1024 float4
          float4 v = src[idx], e = be[idx & 63];
          v.x += e.x; v.y += e.y; v.z += e.z; v.w += e.w;
          dst[idx] = v;
      } }
    if (tid < 128) eb2s[tid] = eb2[tid];
    if (tid < 256) ew3s[tid] = ew3[tid];
    __syncthreads();

    int wid = tid >> 6, lane = tid & 63;
    int lrow = lane & 15, lg = lane >> 4;
    float e30 = eb3[0], e31 = eb3[1];
    const float4* pts4 = (const float4*)pts;
    const float4* pss4 = (const float4*)pss;
    unsigned* CC32 = (unsigned*)CC;

    #pragma unroll 1
    for (int i = 0; i < 2; ++i) {
        int s_local = i * 8 + wid;

        f32x4 acc[8][4];                   // [hf][tf]
        #pragma unroll
        for (int hf = 0; hf < 8; ++hf)
            #pragma unroll
            for (int tf = 0; tf < 4; ++tf) acc[hf][tf] = (f32x4){0.f, 0.f, 0.f, 0.f};

        #pragma unroll
        for (int kk = 0; kk < 8; ++kk) {
            int f0 = kk * 8 + lg * 2;
            float4 pA = pss4[s_local * 64 + f0];
            float4 pB = pss4[s_local * 64 + f0 + 1];
            short8 bf[4];
            #pragma unroll
            for (int tf = 0; tf < 4; ++tf) {
                int tl = tf * 16 + lrow;
                int swz = tl & 7;
                float4 vA = pts4[tl * 64 + (f0 ^ swz)];
                float4 vB = pts4[tl * 64 + ((f0 + 1) ^ swz)];
                U32x4 a;
                a.u[0] = cvtpk(fmaxf(vA.x + pA.x, 0.f), fmaxf(vA.y + pA.y, 0.f));
                a.u[1] = cvtpk(fmaxf(vA.z + pA.z, 0.f), fmaxf(vA.w + pA.w, 0.f));
                a.u[2] = cvtpk(fmaxf(vB.x + pB.x, 0.f), fmaxf(vB.y + pB.y, 0.f));
                a.u[3] = cvtpk(fmaxf(vB.z + pB.z, 0.f), fmaxf(vB.w + pB.w, 0.f));
                bf[tf] = a.s8;
            }
            #pragma unroll
            for (int hf = 0; hf < 8; ++hf) {
                short8 afr = *(const short8*)(ew2s + (((kk * 8 + hf) * 64 + lane) << 3));
                #pragma unroll
                for (int tf = 0; tf < 4; ++tf)
                    acc[hf][tf] = __builtin_amdgcn_mfma_f32_16x16x32_bf16(afr, bf[tf], acc[hf][tf], 0, 0, 0);
            }
        }

        size_t outrow = (size_t)(b * 512 + s0 + s_local) * 512;
        #pragma unroll
        for (int tf = 0; tf < 4; ++tf) {
            float p0 = 0.f, p1 = 0.f;
            #pragma unroll
            for (int hf = 0; hf < 8; ++hf)
                #pragma unroll
                for (int r = 0; r < 4; ++r) {
                    int h = hf * 16 + lg * 4 + r;
                    float hv = fmaxf(acc[hf][tf][r] + eb2s[h], 0.f);
                    p0 += hv * ew3s[2 * h];
                    p1 += hv * ew3s[2 * h + 1];
                }
            p0 += __shfl_xor(p0, 16); p1 += __shfl_xor(p1, 16);
            p0 += __shfl_xor(p0, 32); p1 += __shfl_xor(p1, 32);
            if (lg == 0) {
                int t = t0 + tf * 16 + lrow;
                CC32[outrow + t] = cvtpk(p0 + e30, p1 + e31);
            }
        }
    }
}

// ================================================================ ifft stage 1 (over t), MFMA
__global__ __launch_bounds__(256) void ifft1_mfma(const short* __restrict__ CC,
                                                  const short* __restrict__ F1P,
                                                  short* __restrict__ B2P) {
    __shared__ short st[32 * 128];   // 8 KB
    int bidx = blockIdx.x;           // 256: mt(64) x nt(4)
    int nt = bidx & 3;
    int mt = bidx >> 2;
    int bs0 = mt * 16;
    int b = mt >> 5;
    int kk2 = mt & 31;
    int tid = threadIdx.x, wid = tid >> 6, lane = tid & 63;
    int lrow = lane & 15, lg = lane >> 4;

    f32x4 acc[4];
    #pragma unroll
    for (int f = 0; f < 4; ++f) acc[f] = (f32x4){0.f, 0.f, 0.f, 0.f};

    const short* arow = CC + (size_t)(bs0 + lrow) * 1024 + lg * 8;
    #pragma unroll 4
    for (int kk = 0; kk < 32; ++kk) {
        short8 a = *(const short8*)(arow + kk * 32);
        #pragma unroll
        for (int f = 0; f < 4; ++f) {
            int nfg = nt * 16 + wid * 4 + f;
            short8 bfr = *(const short8*)(F1P + ((kk * 64 + nfg) * 64 + lane) * 8);
            acc[f] = __builtin_amdgcn_mfma_f32_16x16x32_bf16(a, bfr, acc[f], 0, 0, 0);
        }
    }
    #pragma unroll
    for (int f = 0; f < 4; ++f)
        #pragma unroll
        for (int r = 0; r < 4; ++r) {
            int n_local = (wid * 4 + f) * 16 + lrow;    // 0..255
            int lq = n_local >> 1, d = n_local & 1;
            int lk = (lg * 4 + r) * 2 + d;              // 0..31
            st[lk * 128 + lq] = f2bf(acc[f][r]);
        }
    __syncthreads();
    #pragma unroll
    for (int half = 0; half < 2; ++half) {
        int f2 = (tid >> 6) + half * 4;                 // 0..7
        int nf2 = nt * 8 + f2;
        short8 v;
        #pragma unroll
        for (int j = 0; j < 8; ++j)
            v[j] = st[((lane >> 4) * 8 + j) * 128 + f2 * 16 + (lane & 15)];
        *(short8*)(B2P + (size_t)b * 524288 + ((size_t)(kk2 * 32 + nf2) * 64 + lane) * 8) = v;
    }
}

// ================================================================ ifft stage 2 (over s) + scale/sigmoid
__global__ __launch_bounds__(256) void ifft2_mfma(const short* __restrict__ B2P,
                                                  const short* __restrict__ F2,
                                                  const float* __restrict__ alpha, const float* __restrict__ beta,
                                                  float* __restrict__ out) {
    int bidx = blockIdx.x;           // 256: p-tile(32) x qt(4) x b(2)
    int pt_ = bidx & 31;
    int qt = (bidx >> 5) & 3;
    int b = bidx >> 7;
    int p0 = pt_ * 16;
    int tid = threadIdx.x, wid = tid >> 6, lane = tid & 63;
    int lrow = lane & 15, lg = lane >> 4;

    f32x4 acc[2];
    acc[0] = (f32x4){0.f, 0.f, 0.f, 0.f};
    acc[1] = (f32x4){0.f, 0.f, 0.f, 0.f};

    const short* arow = F2 + (size_t)(p0 + lrow) * 1024 + lg * 8;
    const short* bbase = B2P + (size_t)b * 524288;
    #pragma unroll 4
    for (int kk = 0; kk < 32; ++kk) {
        short8 a = *(const short8*)(arow + kk * 32);
        #pragma unroll
        for (int f = 0; f < 2; ++f) {
            int nfg = qt * 8 + wid * 2 + f;
            short8 bfr = *(const short8*)(bbase + ((size_t)(kk * 32 + nfg) * 64 + lane) * 8);
            acc[f] = __builtin_amdgcn_mfma_f32_16x16x32_bf16(a, bfr, acc[f], 0, 0, 0);
        }
    }
    float al = alpha[0], be = beta[0];
    const float scale = 1.0f / (512.0f * 512.0f);
    #pragma unroll
    for (int f = 0; f < 2; ++f)
        #pragma unroll
        for (int r = 0; r < 4; ++r) {
            int q = qt * 128 + (wid * 2 + f) * 16 + lrow;
            int p = p0 + lg * 4 + r;
            float l = al * (acc[f][r] * scale) + be;
            size_t idx = (size_t)b * 262144 + (size_t)p * 512 + q;
            out[idx] = l;
            out[524288 + idx] = 1.f / (1.f + expf(-l));
        }
}

// ================================================================ launch
extern "C" void kernel_launch(void* const* d_in, const int* in_sizes, int n_in,
                              void* d_out, int out_size, void* d_ws, size_t ws_size,
                              hipStream_t stream) {
    const float* spikes = (const float*)d_in[0];
    const float* Wr  = (const float*)d_in[1];
    const float* Wi  = (const float*)d_in[2];
    const float* pw1 = (const float*)d_in[3];
    const float* pb1 = (const float*)d_in[4];
    const float* pw2 = (const float*)d_in[5];
    const float* pb2 = (const float*)d_in[6];
    const float* nw1 = (const float*)d_in[7];
    const float* nb1 = (const float*)d_in[8];
    const float* nw2 = (const float*)d_in[9];
    const float* nb2 = (const float*)d_in[10];
    const float* sw  = (const float*)d_in[11];
    const float* sb  = (const float*)d_in[12];
    const float* tw_ = (const float*)d_in[13];
    const float* tb  = (const float*)d_in[14];
    const float* ew1 = (const float*)d_in[15];
    const float* eb1 = (const float*)d_in[16];
    const float* ew2 = (const float*)d_in[17];
    const float* eb2 = (const float*)d_in[18];
    const float* ew3 = (const float*)d_in[19];
    const float* eb3 = (const float*)d_in[20];
    const float* alpha = (const float*)d_in[21];
    const float* beta  = (const float*)d_in[22];
    float* out = (float*)d_out;
    float* ws  = (float*)d_ws;

    float* H    = ws + 0;                     // 131072
    float* X64P = ws + 131072;                // 4*1024*64 = 262144
    float* PS   = ws + 393216;                // 262144
    float* PT   = ws + 655360;                // 262144
    short* EW2T = (short*)(ws + 917504);      // 32768 shorts
    short* W4P  = (short*)(ws + 933888);      // 262144 shorts
    short* F1P  = (short*)(ws + 1064960);     // 1048576 shorts
    short* F2   = (short*)(ws + 1589248);     // 524288 shorts
    short* CC   = (short*)(ws + 1851392);     // 1048576 shorts -> ends at 2375680 floats (~9.5 MB)
    short* B2P  = (short*)(ws + 393216);      // overlays PS+PT (dead after edge)

    setup_kernel<<<7296, 256, 0, stream>>>(ew2, W4P, F1P, F2, EW2T);
    dft_mfma<<<256, 256, 0, stream>>>(spikes, W4P, X64P);
    k_node<<<256, 128, 0, stream>>>(X64P, Wr, Wi, pw1, pb1, pw2, pb2, nw1, nb1, nw2, nb2, H);
    k_edge_in<<<256, 256, 0, stream>>>(H, sw, sb, tw_, tb, ew1, PS, PT);
    edge_mfma3<<<512, 512, 0, stream>>>(PS, PT, eb1, EW2T, eb2, ew3, eb3, CC);
    ifft1_mfma<<<256, 256, 0, stream>>>(CC, F1P, B2P);
    ifft2_mfma<<<256, 256, 0, stream>>>(B2P, F2, alpha, beta, out);
}

// Round 5
// 145.784 us; speedup vs baseline: 2.4608x; 1.0565x over previous
//
#include <hip/hip_runtime.h>
#include <hip/hip_bf16.h>
#include <math.h>

typedef __attribute__((ext_vector_type(8))) short short8;
typedef __attribute__((ext_vector_type(4))) float f32x4;

__device__ __forceinline__ short f2bf(float x) {
    union { float f; unsigned u; } v; v.f = x;
    unsigned r = v.u + 0x7fffu + ((v.u >> 16) & 1u);   // RNE
    return (short)(r >> 16);
}
__device__ __forceinline__ unsigned cvtpk(float lo, float hi) {
    unsigned r;
    asm("v_cvt_pk_bf16_f32 %0, %1, %2" : "=v"(r) : "v"(lo), "v"(hi));
    return r;
}
union U32x4 { unsigned u[4]; short8 s8; };

// ================================================================ setup: tables via LDS sincos lookup + weight packs
// W4P : B-frags temporal DFT [kkg 128][nf 4][lane][j]  262144 bf16
// F1P : B-frags ifft1        [kk 32][nfg 64][lane][j]  1048576 bf16
// F2  : row-major A ifft2    [p 512][k2 1024]          524288 bf16
// EW2T: A-frags edge L2      [kk 8][hf 8][lane][j]     32768 bf16
// PWP : B-frags mlp4         [l 4][kk 4][nf 8][lane][j] 65536 bf16
__global__ __launch_bounds__(256) void setup_kernel(const float* __restrict__ ew2,
                                                    const float* __restrict__ pw1, const float* __restrict__ pw2,
                                                    const float* __restrict__ nw1, const float* __restrict__ nw2,
                                                    short* __restrict__ W4P, short* __restrict__ F1P,
                                                    short* __restrict__ F2, short* __restrict__ EW2T,
                                                    short* __restrict__ PWP) {
    __shared__ float2 tab[4096];
    int blk = blockIdx.x, tid = threadIdx.x;
    if (blk < 32) {                                    // W4P
        for (int i = tid; i < 4096; i += 256) {
            float sn, cs; sincospif((float)i * (1.0f / 2048.0f), &sn, &cs);
            tab[i] = make_float2(cs, sn);
        }
        __syncthreads();
        int base = blk * 8192;
        #pragma unroll 4
        for (int u = 0; u < 32; ++u) {
            int i = base + u * 256 + tid;
            int j = i & 7, lane = (i >> 3) & 63, nf = (i >> 9) & 3, kkg = i >> 11;
            int k = kkg * 32 + (lane >> 4) * 8 + j;
            int n = nf * 16 + (lane & 15);
            float2 cs = tab[(k * (n & 31)) & 4095];
            W4P[i] = f2bf(n < 32 ? cs.x : -cs.y);
        }
    } else if (blk < 160) {                            // F1P
        for (int i = tid; i < 512; i += 256) {
            float sn, cs; sincospif((float)i * (1.0f / 256.0f), &sn, &cs);
            tab[i] = make_float2(cs, sn);
        }
        __syncthreads();
        int base = (blk - 32) * 8192;
        #pragma unroll 4
        for (int u = 0; u < 32; ++u) {
            int ii = base + u * 256 + tid;
            int j = ii & 7, lane = (ii >> 3) & 63, nfg = (ii >> 9) & 63, kk = ii >> 15;
            int k2 = kk * 32 + (lane >> 4) * 8 + j;
            int t = k2 >> 1, c = k2 & 1;
            int n = nfg * 16 + (lane & 15);
            int q = n >> 1, d = n & 1;
            float2 cs = tab[(t * q) & 511];
            F1P[ii] = f2bf((c == d) ? cs.x : (c ? -cs.y : cs.y));
        }
    } else if (blk < 224) {                            // F2
        for (int i = tid; i < 512; i += 256) {
            float sn, cs; sincospif((float)i * (1.0f / 256.0f), &sn, &cs);
            tab[i] = make_float2(cs, sn);
        }
        __syncthreads();
        int base = (blk - 160) * 8192;
        #pragma unroll 4
        for (int u = 0; u < 32; ++u) {
            int ii = base + u * 256 + tid;
            int p = ii >> 10, k2 = ii & 1023;
            int s = k2 >> 1, dd = k2 & 1;
            float2 cs = tab[(p * s) & 511];
            F2[ii] = f2bf(dd ? -cs.y : cs.x);
        }
    } else {                                           // EW2T + PWP
        int base = (blk - 224) * 8192;
        #pragma unroll 4
        for (int u = 0; u < 32; ++u) {
            int ii = base + u * 256 + tid;
            if (ii < 32768) {
                int j = ii & 7, lane = (ii >> 3) & 63, hf = (ii >> 9) & 7, kk = ii >> 12;
                int k = kk * 32 + (lane >> 4) * 8 + j;
                int h = hf * 16 + (lane & 15);
                EW2T[ii] = f2bf(ew2[k * 128 + h]);
            } else {
                int iw = ii - 32768;                   // [l][kk][nf][lane][j]
                int l = iw >> 14;
                int r = iw & 16383;
                int j = r & 7, lane = (r >> 3) & 63, nf = (r >> 9) & 7, kk = r >> 12;
                int k = kk * 32 + (lane >> 4) * 8 + j;
                int n = nf * 16 + (lane & 15);
                const float* W = (l == 0) ? pw1 : (l == 1) ? pw2 : (l == 2) ? nw1 : nw2;
                PWP[iw] = f2bf(W[k * 128 + n]);
            }
        }
    }
}

// ================================================================ combine: Wps = sw@ew1a, Wpt = tw@ew1b (fp32) -> WCP bf16 frags + BC bias
__global__ __launch_bounds__(512) void k_combine(const float* __restrict__ sw, const float* __restrict__ tw,
                                                 const float* __restrict__ sb, const float* __restrict__ tb,
                                                 const float* __restrict__ ew1,
                                                 short* __restrict__ WCP, float* __restrict__ BC) {
    __shared__ float eL[256][32];
    int blk = blockIdx.x, tid = threadIdx.x;
    int half = blk >> 3, jt = blk & 7, j0 = jt * 32;
    const float* ebase = ew1 + (size_t)half * 256 * 256;
    #pragma unroll
    for (int it = 0; it < 16; ++it) {
        int idx = tid + it * 512;
        int i = idx >> 5, jj = idx & 31;
        eL[i][jj] = ebase[(size_t)i * 256 + j0 + jj];
    }
    __syncthreads();
    const float* wp = half ? tw : sw;
    int d = tid >> 2, jq = tid & 3;
    float acc[8] = {0, 0, 0, 0, 0, 0, 0, 0};
    #pragma unroll 8
    for (int i = 0; i < 256; ++i) {
        float wv = wp[(size_t)d * 256 + i];
        #pragma unroll
        for (int x = 0; x < 8; ++x) acc[x] += wv * eL[i][jq * 8 + x];
    }
    int kk = d >> 5, lg = (d >> 3) & 3, j = d & 7;
    #pragma unroll
    for (int x = 0; x < 8; ++x) {
        int n = half * 256 + j0 + jq * 8 + x;
        int lane = lg * 16 + (n & 15);
        WCP[((kk * 32 + (n >> 4)) * 64 + lane) * 8 + j] = f2bf(acc[x]);
    }
    if (tid < 32) {
        const float* bv = half ? tb : sb;
        float a = 0.f;
        #pragma unroll 8
        for (int i = 0; i < 256; ++i) a += bv[i] * eL[i][tid];
        BC[half * 256 + j0 + tid] = a;
    }
}

// ================================================================ temporal DFT via MFMA, split-k x4
__global__ __launch_bounds__(256) void dft_mfma(const float* __restrict__ spikes,
                                                const short* __restrict__ W4P,
                                                float* __restrict__ X64P) {
    __shared__ float red[4][4][64][4];
    int part = blockIdx.x & 3;
    int row0 = (blockIdx.x >> 2) * 16;
    int tid = threadIdx.x, wid = tid >> 6, lane = tid & 63;
    int lrow = lane & 15, lg = lane >> 4;

    f32x4 acc[4];
    #pragma unroll
    for (int n = 0; n < 4; ++n) acc[n] = (f32x4){0.f, 0.f, 0.f, 0.f};

    int row = row0 + lrow;
    const float* sbase = spikes + (size_t)row * 4096;
    #pragma unroll
    for (int kk = 0; kk < 8; ++kk) {
        int k = part * 1024 + wid * 256 + kk * 32 + lg * 8;
        const float4* sp = (const float4*)(sbase + k);
        float4 v0 = sp[0], v1 = sp[1];
        U32x4 a;
        a.u[0] = cvtpk(v0.x, v0.y);
        a.u[1] = cvtpk(v0.z, v0.w);
        a.u[2] = cvtpk(v1.x, v1.y);
        a.u[3] = cvtpk(v1.z, v1.w);
        int kkg = part * 32 + wid * 8 + kk;
        #pragma unroll
        for (int n = 0; n < 4; ++n) {
            short8 bfr = *(const short8*)(W4P + ((kkg * 4 + n) * 64 + lane) * 8);
            acc[n] = __builtin_amdgcn_mfma_f32_16x16x32_bf16(a.s8, bfr, acc[n], 0, 0, 0);
        }
    }
    #pragma unroll
    for (int n = 0; n < 4; ++n)
        #pragma unroll
        for (int r = 0; r < 4; ++r) red[wid][n][lane][r] = acc[n][r];
    __syncthreads();
    #pragma unroll
    for (int r = 0; r < 4; ++r) {
        float s = red[0][wid][lane][r] + red[1][wid][lane][r]
                + red[2][wid][lane][r] + red[3][wid][lane][r];
        int orow = row0 + lg * 4 + r;
        X64P[(size_t)part * 65536 + (size_t)orow * 64 + wid * 16 + lrow] = s;
    }
}

// ================================================================ energy (wide)
__global__ __launch_bounds__(128) void k_energy(const float* __restrict__ X64P,
                                                const float* __restrict__ Wr, const float* __restrict__ Wi,
                                                float* __restrict__ E) {
    __shared__ float sx[64];
    int row = blockIdx.x, tid = threadIdx.x;
    if (tid < 64) {
        float v = 0.f;
        #pragma unroll
        for (int p = 0; p < 4; ++p) v += X64P[(size_t)p * 65536 + (size_t)row * 64 + tid];
        sx[tid] = v;
    }
    __syncthreads();
    float acc = 0.f;
    #pragma unroll 8
    for (int k = 0; k < 32; ++k) {
        float a = sx[k], b = sx[32 + k];
        float wr = Wr[k * 128 + tid], wi = Wi[k * 128 + tid];
        float yr = a * wr - b * wi;
        float yi = a * wi + b * wr;
        acc += sqrtf(yr * yr + yi * yi + 1e-8f);
    }
    E[(size_t)row * 128 + tid] = acc * (1.0f / 32.0f);
}

// ================================================================ mlp4: 4 chained 128x128 layers, MFMA, M-tile 128
// relu flags: [1,0,1,1]. Output H as bf16 row-major [1024][128].
__global__ __launch_bounds__(512) void k_mlp4(const float* __restrict__ E,
                                              const short* __restrict__ PWP,
                                              const float* __restrict__ pb1, const float* __restrict__ pb2,
                                              const float* __restrict__ nb1, const float* __restrict__ nb2,
                                              short* __restrict__ HP16) {
    __shared__ short abuf[128 * 128];     // 32 KB, XOR-swizzled A storage
    int r0 = blockIdx.x * 128, tid = threadIdx.x;
    int wid = tid >> 6, lane = tid & 63;
    int lrow = lane & 15, lg = lane >> 4;

    #pragma unroll
    for (int it = 0; it < 32; ++it) {
        int idx = tid + it * 512;                  // 16384
        int row = idx >> 7, k = idx & 127;
        abuf[row * 128 + (k ^ ((row & 7) << 3))] = f2bf(E[(size_t)(r0 + row) * 128 + k]);
    }
    __syncthreads();

    #pragma unroll 1
    for (int l = 0; l < 4; ++l) {
        f32x4 acc[8];
        #pragma unroll
        for (int nf = 0; nf < 8; ++nf) acc[nf] = (f32x4){0.f, 0.f, 0.f, 0.f};
        int arow = wid * 16 + lrow;
        int sw_ = (arow & 7) << 3;
        #pragma unroll
        for (int kk = 0; kk < 4; ++kk) {
            int k0 = kk * 32 + lg * 8;
            short8 a = *(const short8*)(abuf + arow * 128 + (k0 ^ sw_));
            #pragma unroll
            for (int nf = 0; nf < 8; ++nf) {
                short8 b = *(const short8*)(PWP + (((l * 4 + kk) * 8 + nf) * 64 + lane) * 8);
                acc[nf] = __builtin_amdgcn_mfma_f32_16x16x32_bf16(a, b, acc[nf], 0, 0, 0);
            }
        }
        __syncthreads();   // done reading abuf, safe to overwrite
        const float* bp = (l == 0) ? pb1 : (l == 1) ? pb2 : (l == 2) ? nb1 : nb2;
        bool rl = (l != 1);
        #pragma unroll
        for (int nf = 0; nf < 8; ++nf) {
            int n = nf * 16 + lrow;
            float bv = bp[n];
            #pragma unroll
            for (int r = 0; r < 4; ++r) {
                int orow = wid * 16 + lg * 4 + r;
                float v = acc[nf][r] + bv;
                if (rl) v = fmaxf(v, 0.f);
                abuf[orow * 128 + (n ^ ((orow & 7) << 3))] = f2bf(v);
            }
        }
        __syncthreads();
    }

    unsigned* hp = (unsigned*)HP16;
    #pragma unroll
    for (int it = 0; it < 16; ++it) {
        int pidx = tid + it * 512;                 // 8192 u32 pairs
        int row = pidx >> 6, kp = pidx & 63;
        unsigned v = *(const unsigned*)(abuf + row * 128 + ((2 * kp) ^ ((row & 7) << 3)));
        hp[(size_t)(r0 + row) * 64 + kp] = v;
    }
}

// ================================================================ ps|pt = H @ Wc + bc  (K=128, N=512), MFMA, M-tile 64
__global__ __launch_bounds__(512) void k_pspt(const short* __restrict__ HP16,
                                              const short* __restrict__ WCP,
                                              const float* __restrict__ BC,
                                              float* __restrict__ PS, float* __restrict__ PT) {
    int m0 = blockIdx.x * 64;
    int tid = threadIdx.x, wid = tid >> 6, lane = tid & 63;
    int lrow = lane & 15, lg = lane >> 4;

    f32x4 acc[4][4];
    #pragma unroll
    for (int mf = 0; mf < 4; ++mf)
        #pragma unroll
        for (int f = 0; f < 4; ++f) acc[mf][f] = (f32x4){0.f, 0.f, 0.f, 0.f};

    #pragma unroll
    for (int kk = 0; kk < 4; ++kk) {
        short8 a[4];
        #pragma unroll
        for (int mf = 0; mf < 4; ++mf)
            a[mf] = *(const short8*)(HP16 + (size_t)(m0 + mf * 16 + lrow) * 128 + kk * 32 + lg * 8);
        #pragma unroll
        for (int f = 0; f < 4; ++f) {
            short8 b = *(const short8*)(WCP + ((kk * 32 + wid * 4 + f) * 64 + lane) * 8);
            #pragma unroll
            for (int mf = 0; mf < 4; ++mf)
                acc[mf][f] = __builtin_amdgcn_mfma_f32_16x16x32_bf16(a[mf], b, acc[mf][f], 0, 0, 0);
        }
    }
    #pragma unroll
    for (int f = 0; f < 4; ++f) {
        int n = (wid * 4 + f) * 16 + lrow;
        float bv = BC[n];
        float* dst = (n < 256) ? (PS + n) : (PT + (n - 256));
        #pragma unroll
        for (int mf = 0; mf < 4; ++mf)
            #pragma unroll
            for (int r = 0; r < 4; ++r) {
                int row = m0 + mf * 16 + lg * 4 + r;
                dst[(size_t)row * 256] = acc[mf][f][r] + bv;
            }
    }
}

// ================================================================ edge MLP v3 + setprio
__global__ __launch_bounds__(512, 2) void edge_mfma3(
    const float* __restrict__ ps, const float* __restrict__ pt,
    const float* __restrict__ eb1, const short* __restrict__ ew2t,
    const float* __restrict__ eb2, const float* __restrict__ ew3,
    const float* __restrict__ eb3, short* __restrict__ CC) {
    __shared__ __align__(16) short ew2s[32768];
    __shared__ __align__(16) float pts[64 * 256];
    __shared__ __align__(16) float pss[16 * 256];
    __shared__ float eb2s[128];
    __shared__ float ew3s[256];

    int bidx = blockIdx.x;
    int ttile = bidx & 7;
    int stile = (bidx >> 3) & 31;
    int b = bidx >> 8;
    int s0 = stile * 16, t0 = ttile * 64;
    int tid = threadIdx.x;

    { const float4* src = (const float4*)ew2t;
      float4* dst = (float4*)ew2s;
      #pragma unroll
      for (int it = 0; it < 8; ++it) dst[tid + it * 512] = src[tid + it * 512]; }
    { const float4* src = (const float4*)(pt + ((size_t)(b * 512 + t0)) * 256);
      float4* dst = (float4*)pts;
      #pragma unroll
      for (int it = 0; it < 8; ++it) {
          int idx = tid + it * 512;
          int tl = idx >> 6, f = idx & 63;
          dst[tl * 64 + (f ^ (tl & 7))] = src[idx];
      } }
    { const float4* src = (const float4*)(ps + ((size_t)(b * 512 + s0)) * 256);
      const float4* be = (const float4*)eb1;
      float4* dst = (float4*)pss;
      #pragma unroll
      for (int it = 0; it < 2; ++it) {
          int idx = tid + it * 512;
          float4 v = src[idx], e = be[idx & 63];
          v.x += e.x; v.y += e.y; v.z += e.z; v.w += e.w;
          dst[idx] = v;
      } }
    if (tid < 128) eb2s[tid] = eb2[tid];
    if (tid < 256) ew3s[tid] = ew3[tid];
    __syncthreads();

    int wid = tid >> 6, lane = tid & 63;
    int lrow = lane & 15, lg = lane >> 4;
    float e30 = eb3[0], e31 = eb3[1];
    const float4* pts4 = (const float4*)pts;
    const float4* pss4 = (const float4*)pss;
    unsigned* CC32 = (unsigned*)CC;

    #pragma unroll 1
    for (int i = 0; i < 2; ++i) {
        int s_local = i * 8 + wid;

        f32x4 acc[8][4];
        #pragma unroll
        for (int hf = 0; hf < 8; ++hf)
            #pragma unroll
            for (int tf = 0; tf < 4; ++tf) acc[hf][tf] = (f32x4){0.f, 0.f, 0.f, 0.f};

        #pragma unroll
        for (int kk = 0; kk < 8; ++kk) {
            int f0 = kk * 8 + lg * 2;
            float4 pA = pss4[s_local * 64 + f0];
            float4 pB = pss4[s_local * 64 + f0 + 1];
            short8 bf[4];
            #pragma unroll
            for (int tf = 0; tf < 4; ++tf) {
                int tl = tf * 16 + lrow;
                int swz = tl & 7;
                float4 vA = pts4[tl * 64 + (f0 ^ swz)];
                float4 vB = pts4[tl * 64 + ((f0 + 1) ^ swz)];
                U32x4 a;
                a.u[0] = cvtpk(fmaxf(vA.x + pA.x, 0.f), fmaxf(vA.y + pA.y, 0.f));
                a.u[1] = cvtpk(fmaxf(vA.z + pA.z, 0.f), fmaxf(vA.w + pA.w, 0.f));
                a.u[2] = cvtpk(fmaxf(vB.x + pB.x, 0.f), fmaxf(vB.y + pB.y, 0.f));
                a.u[3] = cvtpk(fmaxf(vB.z + pB.z, 0.f), fmaxf(vB.w + pB.w, 0.f));
                bf[tf] = a.s8;
            }
            __builtin_amdgcn_s_setprio(1);
            #pragma unroll
            for (int hf = 0; hf < 8; ++hf) {
                short8 afr = *(const short8*)(ew2s + (((kk * 8 + hf) * 64 + lane) << 3));
                #pragma unroll
                for (int tf = 0; tf < 4; ++tf)
                    acc[hf][tf] = __builtin_amdgcn_mfma_f32_16x16x32_bf16(afr, bf[tf], acc[hf][tf], 0, 0, 0);
            }
            __builtin_amdgcn_s_setprio(0);
        }

        size_t outrow = (size_t)(b * 512 + s0 + s_local) * 512;
        #pragma unroll
        for (int tf = 0; tf < 4; ++tf) {
            float p0 = 0.f, p1 = 0.f;
            #pragma unroll
            for (int hf = 0; hf < 8; ++hf)
                #pragma unroll
                for (int r = 0; r < 4; ++r) {
                    int h = hf * 16 + lg * 4 + r;
                    float hv = fmaxf(acc[hf][tf][r] + eb2s[h], 0.f);
                    p0 += hv * ew3s[2 * h];
                    p1 += hv * ew3s[2 * h + 1];
                }
            p0 += __shfl_xor(p0, 16); p1 += __shfl_xor(p1, 16);
            p0 += __shfl_xor(p0, 32); p1 += __shfl_xor(p1, 32);
            if (lg == 0) {
                int t = t0 + tf * 16 + lrow;
                CC32[outrow + t] = cvtpk(p0 + e30, p1 + e31);
            }
        }
    }
}

// ================================================================ ifft stage 1 (over t)
__global__ __launch_bounds__(256) void ifft1_mfma(const short* __restrict__ CC,
                                                  const short* __restrict__ F1P,
                                                  short* __restrict__ B2P) {
    __shared__ short st[32 * 128];
    int bidx = blockIdx.x;
    int nt = bidx & 3;
    int mt = bidx >> 2;
    int bs0 = mt * 16;
    int b = mt >> 5;
    int kk2 = mt & 31;
    int tid = threadIdx.x, wid = tid >> 6, lane = tid & 63;
    int lrow = lane & 15, lg = lane >> 4;

    f32x4 acc[4];
    #pragma unroll
    for (int f = 0; f < 4; ++f) acc[f] = (f32x4){0.f, 0.f, 0.f, 0.f};

    const short* arow = CC + (size_t)(bs0 + lrow) * 1024 + lg * 8;
    #pragma unroll 4
    for (int kk = 0; kk < 32; ++kk) {
        short8 a = *(const short8*)(arow + kk * 32);
        #pragma unroll
        for (int f = 0; f < 4; ++f) {
            int nfg = nt * 16 + wid * 4 + f;
            short8 bfr = *(const short8*)(F1P + ((kk * 64 + nfg) * 64 + lane) * 8);
            acc[f] = __builtin_amdgcn_mfma_f32_16x16x32_bf16(a, bfr, acc[f], 0, 0, 0);
        }
    }
    #pragma unroll
    for (int f = 0; f < 4; ++f)
        #pragma unroll
        for (int r = 0; r < 4; ++r) {
            int n_local = (wid * 4 + f) * 16 + lrow;
            int lq = n_local >> 1, d = n_local & 1;
            int lk = (lg * 4 + r) * 2 + d;
            st[lk * 128 + lq] = f2bf(acc[f][r]);
        }
    __syncthreads();
    #pragma unroll
    for (int half = 0; half < 2; ++half) {
        int f2 = (tid >> 6) + half * 4;
        int nf2 = nt * 8 + f2;
        short8 v;
        #pragma unroll
        for (int j = 0; j < 8; ++j)
            v[j] = st[((lane >> 4) * 8 + j) * 128 + f2 * 16 + (lane & 15)];
        *(short8*)(B2P + (size_t)b * 524288 + ((size_t)(kk2 * 32 + nf2) * 64 + lane) * 8) = v;
    }
}

// ================================================================ ifft stage 2 (over s) + scale/sigmoid
__global__ __launch_bounds__(256) void ifft2_mfma(const short* __restrict__ B2P,
                                                  const short* __restrict__ F2,
                                                  const float* __restrict__ alpha, const float* __restrict__ beta,
                                                  float* __restrict__ out) {
    int bidx = blockIdx.x;
    int pt_ = bidx & 31;
    int qt = (bidx >> 5) & 3;
    int b = bidx >> 7;
    int p0 = pt_ * 16;
    int tid = threadIdx.x, wid = tid >> 6, lane = tid & 63;
    int lrow = lane & 15, lg = lane >> 4;

    f32x4 acc[2];
    acc[0] = (f32x4){0.f, 0.f, 0.f, 0.f};
    acc[1] = (f32x4){0.f, 0.f, 0.f, 0.f};

    const short* arow = F2 + (size_t)(p0 + lrow) * 1024 + lg * 8;
    const short* bbase = B2P + (size_t)b * 524288;
    #pragma unroll 4
    for (int kk = 0; kk < 32; ++kk) {
        short8 a = *(const short8*)(arow + kk * 32);
        #pragma unroll
        for (int f = 0; f < 2; ++f) {
            int nfg = qt * 8 + wid * 2 + f;
            short8 bfr = *(const short8*)(bbase + ((size_t)(kk * 32 + nfg) * 64 + lane) * 8);
            acc[f] = __builtin_amdgcn_mfma_f32_16x16x32_bf16(a, bfr, acc[f], 0, 0, 0);
        }
    }
    float al = alpha[0], be = beta[0];
    const float scale = 1.0f / (512.0f * 512.0f);
    #pragma unroll
    for (int f = 0; f < 2; ++f)
        #pragma unroll
        for (int r = 0; r < 4; ++r) {
            int q = qt * 128 + (wid * 2 + f) * 16 + lrow;
            int p = p0 + lg * 4 + r;
            float l = al * (acc[f][r] * scale) + be;
            size_t idx = (size_t)b * 262144 + (size_t)p * 512 + q;
            out[idx] = l;
            out[524288 + idx] = 1.f / (1.f + expf(-l));
        }
}

// ================================================================ launch
extern "C" void kernel_launch(void* const* d_in, const int* in_sizes, int n_in,
                              void* d_out, int out_size, void* d_ws, size_t ws_size,
                              hipStream_t stream) {
    const float* spikes = (const float*)d_in[0];
    const float* Wr  = (const float*)d_in[1];
    const float* Wi  = (const float*)d_in[2];
    const float* pw1 = (const float*)d_in[3];
    const float* pb1 = (const float*)d_in[4];
    const float* pw2 = (const float*)d_in[5];
    const float* pb2 = (const float*)d_in[6];
    const float* nw1 = (const float*)d_in[7];
    const float* nb1 = (const float*)d_in[8];
    const float* nw2 = (const float*)d_in[9];
    const float* nb2 = (const float*)d_in[10];
    const float* sw  = (const float*)d_in[11];
    const float* sb  = (const float*)d_in[12];
    const float* tw_ = (const float*)d_in[13];
    const float* tb  = (const float*)d_in[14];
    const float* ew1 = (const float*)d_in[15];
    const float* eb1 = (const float*)d_in[16];
    const float* ew2 = (const float*)d_in[17];
    const float* eb2 = (const float*)d_in[18];
    const float* ew3 = (const float*)d_in[19];
    const float* eb3 = (const float*)d_in[20];
    const float* alpha = (const float*)d_in[21];
    const float* beta  = (const float*)d_in[22];
    float* out = (float*)d_out;
    float* ws  = (float*)d_ws;

    // region A (dead before edge writes CC):
    float* X64P = ws + 0;                     // 262144 f
    float* E    = ws + 262144;                // 131072 f
    short* HP16 = (short*)(ws + 393216);      // 65536 sh = 32768 f
    short* WCP  = (short*)(ws + 425984);      // 65536 sh = 32768 f
    float* BC   = ws + 458752;                // 512 f
    short* CC   = (short*)(ws + 0);           // 1048576 sh = 524288 f, overlays region A
    // region B:
    float* PS   = ws + 524288;                // 262144 f
    float* PT   = ws + 786432;                // 262144 f
    short* B2P  = (short*)(ws + 524288);      // overlays PS/PT after edge
    // persistent tables:
    short* EW2T = (short*)(ws + 1048576);     // 32768 sh = 16384 f
    short* W4P  = (short*)(ws + 1064960);     // 262144 sh = 131072 f
    short* F1P  = (short*)(ws + 1196032);     // 1048576 sh = 524288 f
    short* F2   = (short*)(ws + 1720320);     // 524288 sh = 262144 f
    short* PWP  = (short*)(ws + 1982464);     // 65536 sh = 32768 f -> total 2015232 f (8.06 MB)

    setup_kernel<<<236, 256, 0, stream>>>(ew2, pw1, pw2, nw1, nw2, W4P, F1P, F2, EW2T, PWP);
    k_combine<<<16, 512, 0, stream>>>(sw, tw_, sb, tb, ew1, WCP, BC);
    dft_mfma<<<256, 256, 0, stream>>>(spikes, W4P, X64P);
    k_energy<<<1024, 128, 0, stream>>>(X64P, Wr, Wi, E);
    k_mlp4<<<8, 512, 0, stream>>>(E, PWP, pb1, pb2, nb1, nb2, HP16);
    k_pspt<<<16, 512, 0, stream>>>(HP16, WCP, BC, PS, PT);
    edge_mfma3<<<512, 512, 0, stream>>>(PS, PT, eb1, EW2T, eb2, ew3, eb3, CC);
    ifft1_mfma<<<256, 256, 0, stream>>>(CC, F1P, B2P);
    ifft2_mfma<<<256, 256, 0, stream>>>(B2P, F2, alpha, beta, out);
}